// Round 4
// baseline (68.763 us; speedup 1.0000x reference)
//
#include <hip/hip_runtime.h>
#include <hip/hip_bf16.h>
#include <stdint.h>

namespace {

constexpr int N = 4096;      // input length
constexpr int K = 44;        // int(sqrt(2*MAX_PAIRS)) = 44
constexpr float MARGIN = 0.01f;

struct U2 { uint32_t x, y; };

// Threefry-2x32, 20 rounds — constexpr so the key chain folds at compile time.
__host__ __device__ constexpr U2 tf(uint32_t k0, uint32_t k1, uint32_t x0, uint32_t x1) {
  const uint32_t ks0 = k0, ks1 = k1, ks2 = k0 ^ k1 ^ 0x1BD11BDAu;
  uint32_t ks[3] = {ks0, ks1, ks2};
  x0 += ks0; x1 += ks1;
  const int rot0[4] = {13, 15, 26, 6};
  const int rot1[4] = {17, 29, 16, 24};
  for (int i = 0; i < 5; ++i) {
    const int* r = (i & 1) ? rot1 : rot0;
    for (int j = 0; j < 4; ++j) {
      x0 += x1;
      x1 = (x1 << r[j]) | (x1 >> (32 - r[j]));
      x1 ^= x0;
    }
    x0 += ks[(i + 1) % 3];
    x1 += ks[(i + 2) % 3] + (uint32_t)(i + 1);
  }
  return {x0, x1};
}

// jax_threefry_partitionable key chain for key(42):
//   key1, sub1 = split(key);  key2, sub2 = split(key1)
// split: subkey = threefry(key, counter=(0,1)); next key = counter (0,0).
constexpr U2 KEY1 = tf(0u, 42u, 0u, 0u);
constexpr U2 SUB1 = tf(0u, 42u, 0u, 1u);
constexpr U2 SUB2 = tf(KEY1.x, KEY1.y, 0u, 1u);

} // namespace

// ---- kernel 1: fused keys + rank ----
// 64 blocks: pass = b>>5 (round-1 / round-2 keys), i-chunk = b&31 (128 i's).
// Each block regenerates its pass's 4096 composite keys (key<<32|idx, stable)
// into LDS, then each thread ranks R=4 i's against a 128-long j-stride.
__global__ __launch_bounds__(1024)
void RL_rank(uint32_t* __restrict__ rank) {   // rank[pass*N + i]
  __shared__ uint64_t kj[N];                  // 32 KiB
  const int b = blockIdx.x;
  const int pass = b >> 5;
  const int ibase = (b & 31) * 128;
  const int tid = threadIdx.x;
  const U2 sub = pass ? SUB2 : SUB1;

#pragma unroll
  for (int q = 0; q < 4; ++q) {
    const uint32_t j = (uint32_t)tid + q * 1024;
    U2 r = tf(sub.x, sub.y, 0u, j);           // random_bits[j] = y0^y1
    kj[j] = ((uint64_t)(r.x ^ r.y) << 32) | j;
  }
  __syncthreads();

  const int ig = tid >> 5;                    // i-group (4 i's each)
  const int jl = tid & 31;                    // j-lane
  const int i0 = ibase + ig * 4;
  const uint64_t k0 = kj[i0], k1 = kj[i0 + 1], k2 = kj[i0 + 2], k3 = kj[i0 + 3];
  uint32_t c0 = 0, c1 = 0, c2 = 0, c3 = 0;
#pragma unroll 8
  for (int s = 0; s < 128; ++s) {
    // j = jl + 32*s: 32 distinct banks across the j-lanes (2-way aliasing =
    // free); lanes 32-63 (other i-group) read the same address = broadcast.
    const uint64_t v = kj[jl + 32 * s];
    c0 += (v < k0) ? 1u : 0u;
    c1 += (v < k1) ? 1u : 0u;
    c2 += (v < k2) ? 1u : 0u;
    c3 += (v < k3) ? 1u : 0u;
  }
#pragma unroll
  for (int off = 16; off > 0; off >>= 1) {    // reduce over the 32 j-lanes
    c0 += __shfl_xor(c0, off);
    c1 += __shfl_xor(c1, off);
    c2 += __shfl_xor(c2, off);
    c3 += __shfl_xor(c3, off);
  }
  if (jl == 0) {
    rank[pass * N + i0]     = c0;
    rank[pass * N + i0 + 1] = c1;
    rank[pass * N + i0 + 2] = c2;
    rank[pass * N + i0 + 3] = c3;
  }
}

// ---- kernel 2: select + pair loss ----
// Element i's final rank r = rank2[rank1[i]] (round-2 keys attach to round-1
// positions); the sampled idx list is sel[r]=i for r<K, in rank order.
__global__ __launch_bounds__(1024)
void RL_final(const uint32_t* __restrict__ rank,
              const float* __restrict__ pred, const float* __restrict__ targ,
              float* __restrict__ out) {
  __shared__ uint32_t sel[K];
  __shared__ float sp[K], st[K];
  __shared__ float red_sum[16], red_cnt[16];
  const int tid = threadIdx.x;

#pragma unroll
  for (int q = 0; q < 4; ++q) {
    const int i = tid + q * 1024;
    const uint32_t r1 = rank[i];
    const uint32_t r2 = rank[N + r1];
    if (r2 < K) sel[r2] = (uint32_t)i;
  }
  __syncthreads();

  if (tid < K) {
    const uint32_t idx = sel[tid];
    sp[tid] = pred[idx];
    st[tid] = targ[idx];
  }
  __syncthreads();

  // pairwise margin ranking loss over upper triangle (identical to validated R2/R3)
  float lsum = 0.f, lcnt = 0.f;
  for (int q = tid; q < K * K; q += 1024) {
    int i = q / K, j = q % K;
    if (j > i) {
      float ta = st[i], tb = st[j], pa = sp[i], pb = sp[j];
      bool c1 = ta > tb + MARGIN;
      bool c2 = tb > ta + MARGIN;
      float term = c1 ? fmaxf(pb - pa + MARGIN, 0.f)
                      : (c2 ? fmaxf(pa - pb + MARGIN, 0.f) : 0.f);
      lsum += term;
      lcnt += (c1 || c2) ? 1.f : 0.f;
    }
  }
#pragma unroll
  for (int off = 32; off > 0; off >>= 1) {
    lsum += __shfl_down(lsum, off);
    lcnt += __shfl_down(lcnt, off);
  }
  const int wave = tid >> 6, lane = tid & 63;
  if (lane == 0) { red_sum[wave] = lsum; red_cnt[wave] = lcnt; }
  __syncthreads();
  if (tid == 0) {
    float s = 0.f, c = 0.f;
#pragma unroll
    for (int w = 0; w < 16; ++w) { s += red_sum[w]; c += red_cnt[w]; }
    out[0] = (c > 0.f) ? (s / c) : 0.f;
  }
}

extern "C" void kernel_launch(void* const* d_in, const int* in_sizes, int n_in,
                              void* d_out, int out_size, void* d_ws, size_t ws_size,
                              hipStream_t stream) {
  const float* pred = (const float*)d_in[0];
  const float* targ = (const float*)d_in[1];
  float* out = (float*)d_out;
  uint32_t* rank = (uint32_t*)d_ws;   // 32 KiB, fully written before read (no init needed)

  hipLaunchKernelGGL(RL_rank, dim3(64), dim3(1024), 0, stream, rank);
  hipLaunchKernelGGL(RL_final, dim3(1), dim3(1024), 0, stream, rank, pred, targ, out);
}